// Round 7
// baseline (410.702 us; speedup 1.0000x reference)
//
#include <hip/hip_runtime.h>
#include <hip/hip_fp16.h>

#define NCH 128
#define G_NODES 256      // nodes per bucket
#define EPB 4096         // edges per block, pass A
#define RCAP 4864        // per-bucket edge capacity (fixed slab stride)
#define MAXNB 512        // max buckets (N <= 128k)
#define KST 40           // LDS row stride in shorts (80B -> 2-way conflict = free)
#define PEPB 4096        // pairs per block, pbin
#define PCAP 1600        // per-bucket pair capacity (mean 1280, sigma ~36 -> 8.9 sigma)

typedef __attribute__((ext_vector_type(8))) short short8;
typedef _Float16 half8 __attribute__((ext_vector_type(8)));
typedef __attribute__((ext_vector_type(4))) float floatx4;

static inline size_t align256(size_t x){ return (x + 255) & ~(size_t)255; }

// ---------------- Pass A: LDS-binned edge bucketing (+ W-prep tails) ----------------
// Tail work by block index:
//   blocks 0..63   : W1 bf16 hi/lo split
//   blocks 64..191 : W' fold  WA'=W2@Wa, WB'=W2@Wb (f16 hi/lo planes)
//   block  192     : bm1' = bm1 + b2@Wa + b2@Wb ; zbias = 0
__global__ __launch_bounds__(256) void binA_kernel(
    const int* __restrict__ row, const int* __restrict__ col,
    int* __restrict__ gcur, unsigned* __restrict__ bucketed, int E, int NB,
    const float* __restrict__ W1, const float* __restrict__ W2,
    const float* __restrict__ Wm1, const float* __restrict__ b2,
    const float* __restrict__ bm1, short* __restrict__ planes,
    float* __restrict__ bm1p, float* __restrict__ zbias){
  __shared__ int cnt[MAXNB];
  __shared__ int lbase[MAXNB];
  __shared__ int gbase[MAXNB];
  __shared__ unsigned sorted[EPB];
  __shared__ unsigned short binOf[EPB];
  __shared__ int sh[256];
  __shared__ int carry;
  __shared__ float w2row[128];
  int t = threadIdx.x;
  int e0 = blockIdx.x * EPB;
  int ecnt = min(EPB, E - e0);
  for (int i = t; i < NB; i += 256) cnt[i] = 0;
  if (t == 0) carry = 0;
  __syncthreads();
  unsigned rec[16]; int bn[16]; int rk[16];
  #pragma unroll
  for (int i = 0; i < 16; i++){
    int e = e0 + i * 256 + t;
    if (e < E){
      int r = row[e], c = col[e];
      bn[i]  = c >> 8;
      rec[i] = (unsigned)r | ((unsigned)(c & 255) << 17);
      rk[i]  = atomicAdd(&cnt[bn[i]], 1);
    } else bn[i] = -1;
  }
  __syncthreads();
  for (int start = 0; start < NB; start += 256){
    int i = start + t;
    int v = (i < NB) ? cnt[i] : 0;
    sh[t] = v; __syncthreads();
    for (int off = 1; off < 256; off <<= 1){
      int val = (t >= off) ? sh[t - off] : 0;
      __syncthreads(); sh[t] += val; __syncthreads();
    }
    if (i < NB) lbase[i] = sh[t] - v + carry;
    __syncthreads();
    if (t == 255) carry += sh[255];
    __syncthreads();
  }
  for (int i = t; i < NB; i += 256){
    int c = cnt[i];
    gbase[i] = (c > 0) ? atomicAdd(&gcur[i], c) : 0;
  }
  __syncthreads();
  #pragma unroll
  for (int i = 0; i < 16; i++){
    if (bn[i] >= 0){
      int pos = lbase[bn[i]] + rk[i];
      sorted[pos] = rec[i];
      binOf[pos]  = (unsigned short)bn[i];
    }
  }
  __syncthreads();
  for (int idx = t; idx < ecnt; idx += 256){
    int b = binOf[idx];
    int gpos = gbase[b] + (idx - lbase[b]);
    if (gpos < RCAP) bucketed[(size_t)b * RCAP + gpos] = sorted[idx];
  }
  // ---- W1-prep tail (blocks 0..63): bf16 hi/lo split ----
  {
    int gid = blockIdx.x * 256 + t;
    if (gid < 16384){
      int k = gid >> 7, n = gid & 127;
      float x = W1[gid];
      unsigned u = __float_as_uint(x);
      short hs = (short)(u >> 16);
      float hf = __uint_as_float(u & 0xFFFF0000u);
      short ls = (short)(__float_as_uint(x - hf) >> 16);
      planes[n * 128 + k]         = hs;
      planes[16384 + n * 128 + k] = ls;
    }
  }
  // ---- W' fold tail (blocks 64..191): one W2 row per block ----
  if (blockIdx.x >= 64 && blockIdx.x < 192){
    int b = blockIdx.x - 64;
    if (t < 128) w2row[t] = W2[b * 128 + t];
    __syncthreads();
    int mat = t >> 7, n = t & 127;
    const float* Wsrc = Wm1 + (size_t)mat * 16384;
    float acc = 0.f;
    #pragma unroll 4
    for (int j = 0; j < 128; j++) acc = fmaf(w2row[j], Wsrc[j * 128 + n], acc);
    __half hh = __float2half(acc);
    __half ll = __float2half(acc - __half2float(hh));
    planes[(size_t)(4 + 2 * mat) * 16384 + n * 128 + b] = __half_as_short(hh);
    planes[(size_t)(5 + 2 * mat) * 16384 + n * 128 + b] = __half_as_short(ll);
  } else if (blockIdx.x == 192){
    if (t < 128){
      float acc = bm1[t];
      for (int j = 0; j < 128; j++)
        acc += b2[j] * (Wm1[j * 128 + t] + Wm1[(128 + j) * 128 + t]);
      bm1p[t] = acc;
      zbias[t] = 0.f;
    }
  }
}

// ---------------- Pair binning: bucket pairs by src>>8 into fixed slabs ----------------
// rec = idx(19b) | dst(17b)<<19 | src(17b)<<36
__global__ __launch_bounds__(256) void pbin_kernel(
    const int* __restrict__ src, const int* __restrict__ dst,
    int* __restrict__ pcur, unsigned long long* __restrict__ pslab, int P, int NB){
  __shared__ int cnt[MAXNB];
  __shared__ int gbase[MAXNB];
  int t = threadIdx.x;
  int p0 = blockIdx.x * PEPB;
  for (int i = t; i < NB; i += 256) cnt[i] = 0;
  __syncthreads();
  unsigned long long rec[16]; int bn[16]; int rk[16];
  #pragma unroll
  for (int i = 0; i < 16; i++){
    int p = p0 + i * 256 + t;
    if (p < P){
      int s = src[p], d = dst[p];
      bn[i] = s >> 8;
      rec[i] = (unsigned long long)p
             | ((unsigned long long)d << 19)
             | ((unsigned long long)s << 36);
      rk[i] = atomicAdd(&cnt[bn[i]], 1);
    } else bn[i] = -1;
  }
  __syncthreads();
  for (int i = t; i < NB; i += 256){
    int c = cnt[i];
    gbase[i] = (c > 0) ? atomicAdd(&pcur[i], c) : 0;
  }
  __syncthreads();
  #pragma unroll
  for (int i = 0; i < 16; i++){
    if (bn[i] >= 0){
      int pos = gbase[bn[i]] + rk[i];
      if (pos < PCAP) pslab[(size_t)bn[i] * PCAP + pos] = rec[i];
    }
  }
}

// ---------------- Fused launch: gemm_f32 (blocks < gemmBlocks) || binB (rest) ----------------
// gemm side writes UNscaled t1 = x@W1 (dinv produced by binB in same dispatch).
__global__ __launch_bounds__(512, 4) void fused_gemm_binB(
    const float* __restrict__ X, const short* __restrict__ Whi_,
    const short* __restrict__ Wlo_, __half* __restrict__ O, int nrows, int gemmBlocks,
    const unsigned* __restrict__ bucketed, const int* __restrict__ gcur,
    int* __restrict__ rows_sorted, int* __restrict__ offs,
    int* __restrict__ counts, float* __restrict__ dinv, int N){
  __shared__ __align__(16) char smem[40960];
  int t = threadIdx.x;
  if (blockIdx.x < gemmBlocks){
    short* Xhi = (short*)smem;
    short* Xlo = Xhi + 128 * KST;
    short* Whi = Xlo + 128 * KST;
    short* Wlo = Whi + 128 * KST;
    int w = t >> 6, lane = t & 63;
    int m = lane & 15, q = lane >> 4;
    int row0 = blockIdx.x * 128;
    floatx4 acc[8];
    #pragma unroll
    for (int ct = 0; ct < 8; ct++) acc[ct] = (floatx4)0.f;
    for (int kc = 0; kc < 4; kc++){
      int k0 = kc * 32;
      __syncthreads();
      #pragma unroll
      for (int qq = 0; qq < 2; qq++){
        int f = t + 512 * qq;
        int r = f >> 3, kq = f & 7;
        int gr = row0 + r;
        int grc = (gr < nrows) ? gr : 0;
        float4 v = *(const float4*)(X + (size_t)grc * NCH + k0 + kq * 4);
        short h[4], l[4];
        float vv[4] = {v.x, v.y, v.z, v.w};
        #pragma unroll
        for (int j = 0; j < 4; j++){
          unsigned u = __float_as_uint(vv[j]);
          h[j] = (short)(u >> 16);
          float hf = __uint_as_float(u & 0xFFFF0000u);
          l[j] = (short)(__float_as_uint(vv[j] - hf) >> 16);
        }
        *(uint2*)(Xhi + r * KST + kq * 4) = *(uint2*)h;
        *(uint2*)(Xlo + r * KST + kq * 4) = *(uint2*)l;
      }
      {
        int n = t >> 2, kq = t & 3;
        *(uint4*)(Whi + n * KST + kq * 8) = *(const uint4*)(Whi_ + n * NCH + k0 + kq * 8);
        *(uint4*)(Wlo + n * KST + kq * 8) = *(const uint4*)(Wlo_ + n * NCH + k0 + kq * 8);
      }
      __syncthreads();
      short8 a_hi = *(const short8*)(Xhi + (w * 16 + m) * KST + q * 8);
      short8 a_lo = *(const short8*)(Xlo + (w * 16 + m) * KST + q * 8);
      #pragma unroll
      for (int ct = 0; ct < 8; ct++){
        short8 b_hi = *(const short8*)(Whi + (ct * 16 + m) * KST + q * 8);
        short8 b_lo = *(const short8*)(Wlo + (ct * 16 + m) * KST + q * 8);
        acc[ct] = __builtin_amdgcn_mfma_f32_16x16x32_bf16(a_hi, b_hi, acc[ct], 0, 0, 0);
        acc[ct] = __builtin_amdgcn_mfma_f32_16x16x32_bf16(a_lo, b_hi, acc[ct], 0, 0, 0);
        acc[ct] = __builtin_amdgcn_mfma_f32_16x16x32_bf16(a_hi, b_lo, acc[ct], 0, 0, 0);
      }
    }
    #pragma unroll
    for (int r = 0; r < 4; r++){
      int grow = row0 + w * 16 + q * 4 + r;
      if (grow < nrows){
        #pragma unroll
        for (int ct = 0; ct < 8; ct++)
          O[(size_t)grow * NCH + ct * 16 + m] = __float2half(acc[ct][r]);
      }
    }
  } else {
    // ---- binB: per-bucket LDS counting sort -> CSR (fixed slabs) ----
    int b = blockIdx.x - gemmBlocks;
    unsigned* ledge = (unsigned*)smem;              // RCAP
    int* cnt  = (int*)(smem + RCAP * 4);            // 256
    int* cnt2 = cnt + 256;
    int* lex  = cnt2 + 256;
    int* sh   = lex + 256;
    int size = min(gcur[b], RCAP);
    int n0 = b * G_NODES;
    if (t < 256){ cnt[t] = 0; cnt2[t] = 0; }
    __syncthreads();
    for (int i = t; i < size; i += 512){
      unsigned v = bucketed[(size_t)b * RCAP + i];
      ledge[i] = v;
      atomicAdd(&cnt[v >> 17], 1);
    }
    __syncthreads();
    {
      int v = (t < 256) ? cnt[t] : 0;
      if (t < 256) sh[t] = v;
      __syncthreads();
      for (int off = 1; off < 256; off <<= 1){
        int val = (t >= off && t < 256) ? sh[t - off] : 0;
        __syncthreads();
        if (t < 256) sh[t] += val;
        __syncthreads();
      }
      if (t < 256){
        lex[t] = sh[t] - v;
        int n = n0 + t;
        if (n < N){
          counts[n] = v;
          offs[n]   = b * RCAP + sh[t] - v;
          dinv[n]   = rsqrtf((float)v + 1.0f);
        }
      }
    }
    __syncthreads();
    for (int i = t; i < size; i += 512){
      unsigned v = ledge[i];
      int node = v >> 17;
      int pos = lex[node] + atomicAdd(&cnt2[node], 1);
      rows_sorted[(size_t)b * RCAP + pos] = (int)(v & 0x1FFFFu);
    }
  }
}

// ---------------- GEMM (fp16 input): 2-MFMA f16, NCT col-tiles, opt. dinv scale ----------------
template<int NCT>
__global__ __launch_bounds__(512, 4) void gemm_f16k(
    const __half* __restrict__ X,
    const short* __restrict__ Whi0, const short* __restrict__ Wlo0,
    const short* __restrict__ Whi1, const short* __restrict__ Wlo1,
    const float* __restrict__ scale, int do_scale,
    __half* __restrict__ O0, __half* __restrict__ O1, int nrows){
  __shared__ short Xs[128 * KST];
  __shared__ short Whs[NCT * 16 * KST];
  __shared__ short Wls[NCT * 16 * KST];
  int t = threadIdx.x;
  int w = t >> 6, lane = t & 63;
  int m = lane & 15, q = lane >> 4;
  int row0 = blockIdx.x * 128;
  floatx4 acc[NCT];
  #pragma unroll
  for (int ct = 0; ct < NCT; ct++) acc[ct] = (floatx4)0.f;

  for (int kc = 0; kc < 4; kc++){
    int k0 = kc * 32;
    __syncthreads();
    {
      int r = t >> 2, kq = t & 3;
      int gr = row0 + r;
      int grc = (gr < nrows) ? gr : 0;
      *(uint4*)(Xs + r * KST + kq * 8) = *(const uint4*)(X + (size_t)grc * NCH + k0 + kq * 8);
    }
    #pragma unroll
    for (int i = t; i < NCT * 16 * 4; i += 512){
      int n = i >> 2, kq = i & 3;
      const short* sh = (n < 128) ? (Whi0 + n * NCH) : (Whi1 + (n - 128) * NCH);
      const short* sl = (n < 128) ? (Wlo0 + n * NCH) : (Wlo1 + (n - 128) * NCH);
      *(uint4*)(Whs + n * KST + kq * 8) = *(const uint4*)(sh + k0 + kq * 8);
      *(uint4*)(Wls + n * KST + kq * 8) = *(const uint4*)(sl + k0 + kq * 8);
    }
    __syncthreads();
    half8 a = *(const half8*)(Xs + (w * 16 + m) * KST + q * 8);
    #pragma unroll
    for (int ct = 0; ct < NCT; ct++){
      half8 bh = *(const half8*)(Whs + (ct * 16 + m) * KST + q * 8);
      half8 bl = *(const half8*)(Wls + (ct * 16 + m) * KST + q * 8);
      acc[ct] = __builtin_amdgcn_mfma_f32_16x16x32_f16(a, bh, acc[ct], 0, 0, 0);
      acc[ct] = __builtin_amdgcn_mfma_f32_16x16x32_f16(a, bl, acc[ct], 0, 0, 0);
    }
  }
  #pragma unroll
  for (int r = 0; r < 4; r++){
    int grow = row0 + w * 16 + q * 4 + r;
    if (grow < nrows){
      float sc = do_scale ? scale[grow] : 1.0f;
      #pragma unroll
      for (int ct = 0; ct < NCT; ct++){
        __half val = __float2half(acc[ct][r] * sc);
        if (ct < 8) O0[(size_t)grow * NCH + ct * 16 + m] = val;
        else        O1[(size_t)grow * NCH + (ct - 8) * 16 + m] = val;
      }
    }
  }
}

// ---------------- GCN aggregation: wave per node, 16B/lane gathers ----------------
__global__ __launch_bounds__(256) void agg_kernel(
    const __half* __restrict__ s, const float* __restrict__ dinv,
    const int* __restrict__ offs, const int* __restrict__ counts,
    const int* __restrict__ rows_sorted, const float* __restrict__ bias,
    __half* __restrict__ outp, int N, int do_relu, int edge_dinv){
  int wave = (int)((blockIdx.x * blockDim.x + threadIdx.x) >> 6);
  int lane = threadIdx.x & 63;
  if (wave >= N) return;
  int c = wave;
  int g = lane >> 4, h = lane & 15;
  float di = dinv[c];
  float wself = edge_dinv ? di : 1.0f;
  float acc[8] = {0.f,0.f,0.f,0.f,0.f,0.f,0.f,0.f};
  if (g == 0){
    uint4 v = *(const uint4*)(s + (size_t)c * NCH + h * 8);
    const __half2* hp = (const __half2*)&v;
    #pragma unroll
    for (int i = 0; i < 4; i++){
      float2 f = __half22float2(hp[i]);
      acc[2*i] = fmaf(wself, f.x, acc[2*i]); acc[2*i+1] = fmaf(wself, f.y, acc[2*i+1]);
    }
  }
  int off = offs[c], cnt = counts[c];
  for (int chunk = 0; chunk < cnt; chunk += 64){
    int nn = min(64, cnt - chunk);
    int myidx = (lane < nn) ? rows_sorted[off + chunk + lane] : 0;
    float mydinv = 1.0f;
    if (edge_dinv && lane < nn) mydinv = dinv[myidx];
    int jmax = (nn + 3) >> 2;
    #pragma unroll 8
    for (int j = 0; j < jmax; j++){
      int e = 4 * j + g;
      int r  = __shfl(myidx, e & 63, 64);
      float dr = edge_dinv ? __shfl(mydinv, e & 63, 64) : 1.0f;
      if (e < nn){
        uint4 v = *(const uint4*)(s + (size_t)r * NCH + h * 8);
        const __half2* hp = (const __half2*)&v;
        #pragma unroll
        for (int i = 0; i < 4; i++){
          float2 f = __half22float2(hp[i]);
          acc[2*i] = fmaf(dr, f.x, acc[2*i]); acc[2*i+1] = fmaf(dr, f.y, acc[2*i+1]);
        }
      }
    }
  }
  #pragma unroll
  for (int i = 0; i < 8; i++){
    acc[i] += __shfl_xor(acc[i], 16, 64);
    acc[i] += __shfl_xor(acc[i], 32, 64);
  }
  if (g == 0){
    float4 b0 = *(const float4*)(bias + h * 8);
    float4 b1 = *(const float4*)(bias + h * 8 + 4);
    float o[8];
    o[0] = di*acc[0]+b0.x; o[1] = di*acc[1]+b0.y; o[2] = di*acc[2]+b0.z; o[3] = di*acc[3]+b0.w;
    o[4] = di*acc[4]+b1.x; o[5] = di*acc[5]+b1.y; o[6] = di*acc[6]+b1.z; o[7] = di*acc[7]+b1.w;
    if (do_relu){
      #pragma unroll
      for (int i = 0; i < 8; i++) o[i] = fmaxf(o[i], 0.f);
    }
    __half2 packed[4];
    #pragma unroll
    for (int i = 0; i < 4; i++) packed[i] = __floats2half2_rn(o[2*i], o[2*i+1]);
    *(uint4*)(outp + (size_t)c * NCH + h * 8) = *(uint4*)packed;
  }
}

// ---------------- Pair head v2: bucketed by src for A-side L2 locality ----------------
// 2 blocks per bucket (interleaved chunks); each wave 16 pairs as before; output
// scattered to original pair index. A-rows of a bucket form a 64KB L2-resident window.
__global__ __launch_bounds__(256) void pair2_kernel(
    const __half* __restrict__ A, const __half* __restrict__ B,
    const int* __restrict__ pcur, const unsigned long long* __restrict__ pslab,
    const float* __restrict__ bm1, const float* __restrict__ Wm2,
    const float* __restrict__ bm2, float* __restrict__ outp, int P, int NB){
  int bucket = blockIdx.x >> 1;
  int half = blockIdx.x & 1;
  if (bucket >= NB) return;
  int t = threadIdx.x;
  int wv = t >> 6, lane = t & 63;
  int g = lane >> 4, h = lane & 15;
  float bb[8], ww[8];
  {
    float4 t0 = *(const float4*)(bm1 + h * 8);
    float4 t1 = *(const float4*)(bm1 + h * 8 + 4);
    bb[0]=t0.x; bb[1]=t0.y; bb[2]=t0.z; bb[3]=t0.w;
    bb[4]=t1.x; bb[5]=t1.y; bb[6]=t1.z; bb[7]=t1.w;
    float4 w0 = *(const float4*)(Wm2 + h * 8);
    float4 w1 = *(const float4*)(Wm2 + h * 8 + 4);
    ww[0]=w0.x; ww[1]=w0.y; ww[2]=w0.z; ww[3]=w0.w;
    ww[4]=w1.x; ww[5]=w1.y; ww[6]=w1.z; ww[7]=w1.w;
  }
  float bsc = bm2[0];
  const __half* basep = (g & 1) ? B : A;
  int s = g >> 1;
  int cnt = min(pcur[bucket], PCAP);
  const unsigned long long* slab = pslab + (size_t)bucket * PCAP;
  int nch = (cnt + 63) >> 6;
  for (int ch = half; ch < nch; ch += 2){
    int base = ch * 64 + wv * 16;
    unsigned long long rec = 0;
    {
      int pl = base + (lane & 15);
      if (pl < cnt) rec = slab[pl];
    }
    int pi[8]; uint4 v[8];
    #pragma unroll
    for (int k = 0; k < 8; k++){
      int j = 2 * k + s;
      unsigned long long r = __shfl(rec, j, 64);
      int orig = (int)(r & 0x7FFFFULL);
      int dnode = (int)((r >> 19) & 0x1FFFFULL);
      int snode = (int)((r >> 36) & 0x1FFFFULL);
      int node = (g & 1) ? dnode : snode;
      pi[k] = (base + j < cnt) ? orig : -1;
      v[k] = *(const uint4*)(basep + (size_t)node * NCH + h * 8);
    }
    float pr[8];
    #pragma unroll
    for (int k = 0; k < 8; k++){
      const __half2* hp = (const __half2*)&v[k];
      float f[8];
      #pragma unroll
      for (int i = 0; i < 4; i++){
        float2 t2 = __half22float2(hp[i]);
        f[2*i] = t2.x; f[2*i+1] = t2.y;
      }
      float p_ = 0.f;
      #pragma unroll
      for (int i = 0; i < 8; i++){
        float o = __shfl_xor(f[i], 16, 64);
        p_ += fmaxf(f[i] + o + bb[i], 0.f) * ww[i];
      }
      pr[k] = p_;
    }
    #pragma unroll
    for (int k = 0; k < 8; k++){
      #pragma unroll
      for (int d = 1; d <= 8; d <<= 1) pr[k] += __shfl_xor(pr[k], d, 64);
    }
    if ((lane & 31) == 0){
      #pragma unroll
      for (int k = 0; k < 8; k++)
        if (pi[k] >= 0) outp[pi[k]] = pr[k] + bsc;
    }
  }
}

// ---------------- launch ----------------

extern "C" void kernel_launch(void* const* d_in, const int* in_sizes, int n_in,
                              void* d_out, int out_size, void* d_ws, size_t ws_size,
                              hipStream_t stream){
  const float* x   = (const float*)d_in[0];
  const int*   ei  = (const int*)  d_in[1];
  const int*   ep  = (const int*)  d_in[2];
  const float* W1  = (const float*)d_in[3];
  const float* b1  = (const float*)d_in[4];
  const float* W2  = (const float*)d_in[5];
  const float* b2  = (const float*)d_in[6];
  const float* Wm1 = (const float*)d_in[7];
  const float* bm1 = (const float*)d_in[8];
  const float* Wm2 = (const float*)d_in[9];
  const float* bm2 = (const float*)d_in[10];
  float* outp = (float*)d_out;

  const int N = in_sizes[0] / NCH;
  const int E = in_sizes[1] / 2;
  const int P = in_sizes[2] / 2;
  const int NB = (N + G_NODES - 1) / G_NODES;

  char* base = (char*)d_ws;
  size_t off = 0;
  int*      counts      = (int*)     (base + off); off = align256(off + (size_t)N * 4);
  int*      offs        = (int*)     (base + off); off = align256(off + (size_t)N * 4);
  float*    dinv        = (float*)   (base + off); off = align256(off + (size_t)N * 4);
  int*      gcur        = (int*)     (base + off); off = align256(off + (size_t)2 * NB * 4);
  unsigned* bucketed    = (unsigned*)(base + off); off = align256(off + (size_t)NB * RCAP * 4);
  int*      rows_sorted = (int*)     (base + off); off = align256(off + (size_t)NB * RCAP * 4);
  unsigned long long* pslab = (unsigned long long*)(base + off);
                                                   off = align256(off + (size_t)NB * PCAP * 8);
  short*    planes      = (short*)   (base + off); off = align256(off + (size_t)8 * 16384 * 2);
  float*    bm1p        = (float*)   (base + off); off = align256(off + (size_t)256 * 4);
  float*    zbias       = (float*)   (base + off); off = align256(off + (size_t)128 * 4);
  __half*   s1buf       = (__half*)  (base + off); off = align256(off + (size_t)N * NCH * 2);
  __half*   h1buf       = (__half*)  (base + off); off = align256(off + (size_t)N * NCH * 2);
  __half*   zbuf        = (__half*)  (base + off); off = align256(off + (size_t)N * NCH * 2);
  __half*   sA          = (__half*)  (base + off); off = align256(off + (size_t)N * NCH * 2);
  __half*   sB          = (__half*)  (base + off); off = align256(off + (size_t)N * NCH * 2);
  (void)ws_size; (void)n_in; (void)out_size;

  int* pcur = gcur + NB;   // pair-bucket cursors (zeroed by same memset)

  short* W1hi = planes + 0 * 16384;
  short* W1lo = planes + 1 * 16384;
  short* Wahi = planes + 4 * 16384;   // WA' = W2@Wa (hi)
  short* Walo = planes + 5 * 16384;   // WA' (lo)
  short* Wbhi = planes + 6 * 16384;   // WB' = W2@Wb (hi)
  short* Wblo = planes + 7 * 16384;   // WB' (lo)

  const int* row = ei;       // edge_index[0] = source
  const int* col = ei + E;   // edge_index[1] = target
  const int* psrc = ep;
  const int* pdst = ep + P;

  int gemm_grid = (N + 127) / 128;
  int agg_grid  = (N + 3) / 4;
  int binA_grid = (E + EPB - 1) / EPB;
  if (binA_grid < 193) binA_grid = 193;   // W'-fold tail needs blocks 64..192

  // 0: zero bucket cursors (edge + pair)
  hipMemsetAsync(gcur, 0, (size_t)2 * NB * 4, stream);
  // 0b: pair binning by src bucket (independent of everything else)
  pbin_kernel<<<(P + PEPB - 1) / PEPB, 256, 0, stream>>>(psrc, pdst, pcur, pslab, P, NB);
  // 1: edge bucketing + W1/W'-fold/bias tails
  binA_kernel<<<binA_grid, 256, 0, stream>>>(row, col, gcur, bucketed, E, NB,
                                             W1, W2, Wm1, b2, bm1, planes, bm1p, zbias);
  // 2: fused conv1 GEMM (t1 = x@W1, UNscaled) || CSR finalize (no shared data -> no race)
  fused_gemm_binB<<<gemm_grid + NB, 512, 0, stream>>>(
      x, W1hi, W1lo, s1buf, N, gemm_grid,
      bucketed, gcur, rows_sorted, offs, counts, dinv, N);
  // 3: conv1 agg (edge-dinv): h1 = relu(dinv*(dinv*t1[c]+sum dinv[r]t1[r])+b1)
  agg_kernel<<<agg_grid, 256, 0, stream>>>(s1buf, dinv, offs, counts, rows_sorted, b1, h1buf, N, 1, 1);
  // 4: conv2 agg (edge-dinv, zero bias, no relu): z = dinv*(dinv*h1[c]+sum dinv[r]h1[r])
  agg_kernel<<<agg_grid, 256, 0, stream>>>(h1buf, dinv, offs, counts, rows_sorted, zbias, zbuf, N, 0, 1);
  // 5: pair precompute (dual, folded): sA = z@WA', sB = z@WB'
  gemm_f16k<16><<<gemm_grid, 512, 0, stream>>>(zbuf, Wahi, Walo, Wbhi, Wblo, dinv, 0, sA, sB, N);
  // 6: out[orig] = relu(A[src]+B[dst]+bm1')@Wm2 + bm2  (bucketed, L2-local A side)
  pair2_kernel<<<2 * NB, 256, 0, stream>>>(sA, sB, pcur, pslab, bm1p, Wm2, bm2, outp, P, NB);
}

// Round 8
// 370.716 us; speedup vs baseline: 1.1079x; 1.1079x over previous
//
#include <hip/hip_runtime.h>
#include <hip/hip_fp16.h>

#define NCH 128
#define G_NODES 256      // nodes per bucket
#define EPB 4096         // edges per block, pass A
#define RCAP 4864        // per-bucket edge capacity (fixed slab stride)
#define MAXNB 512        // max buckets (N <= 128k)
#define KST 40           // LDS row stride in shorts (80B -> 2-way conflict = free)

typedef __attribute__((ext_vector_type(8))) short short8;
typedef _Float16 half8 __attribute__((ext_vector_type(8)));
typedef __attribute__((ext_vector_type(4))) float floatx4;

static inline size_t align256(size_t x){ return (x + 255) & ~(size_t)255; }

// ---------------- Pass A: LDS-binned edge bucketing (+ W-prep tails) ----------------
// Tail work by block index:
//   blocks 0..63   : W1 bf16 hi/lo split
//   blocks 64..191 : W' fold  WA'=W2@Wa, WB'=W2@Wb (f16 hi/lo planes)
//   block  192     : bm1' = bm1 + b2@Wa + b2@Wb ; zbias = 0
__global__ __launch_bounds__(256) void binA_kernel(
    const int* __restrict__ row, const int* __restrict__ col,
    int* __restrict__ gcur, unsigned* __restrict__ bucketed, int E, int NB,
    const float* __restrict__ W1, const float* __restrict__ W2,
    const float* __restrict__ Wm1, const float* __restrict__ b2,
    const float* __restrict__ bm1, short* __restrict__ planes,
    float* __restrict__ bm1p, float* __restrict__ zbias){
  __shared__ int cnt[MAXNB];
  __shared__ int lbase[MAXNB];
  __shared__ int gbase[MAXNB];
  __shared__ unsigned sorted[EPB];
  __shared__ unsigned short binOf[EPB];
  __shared__ int sh[256];
  __shared__ int carry;
  __shared__ float w2row[128];
  int t = threadIdx.x;
  int e0 = blockIdx.x * EPB;
  int ecnt = min(EPB, E - e0);
  for (int i = t; i < NB; i += 256) cnt[i] = 0;
  if (t == 0) carry = 0;
  __syncthreads();
  unsigned rec[16]; int bn[16]; int rk[16];
  #pragma unroll
  for (int i = 0; i < 16; i++){
    int e = e0 + i * 256 + t;
    if (e < E){
      int r = row[e], c = col[e];
      bn[i]  = c >> 8;
      rec[i] = (unsigned)r | ((unsigned)(c & 255) << 17);
      rk[i]  = atomicAdd(&cnt[bn[i]], 1);
    } else bn[i] = -1;
  }
  __syncthreads();
  for (int start = 0; start < NB; start += 256){
    int i = start + t;
    int v = (i < NB) ? cnt[i] : 0;
    sh[t] = v; __syncthreads();
    for (int off = 1; off < 256; off <<= 1){
      int val = (t >= off) ? sh[t - off] : 0;
      __syncthreads(); sh[t] += val; __syncthreads();
    }
    if (i < NB) lbase[i] = sh[t] - v + carry;
    __syncthreads();
    if (t == 255) carry += sh[255];
    __syncthreads();
  }
  for (int i = t; i < NB; i += 256){
    int c = cnt[i];
    gbase[i] = (c > 0) ? atomicAdd(&gcur[i], c) : 0;
  }
  __syncthreads();
  #pragma unroll
  for (int i = 0; i < 16; i++){
    if (bn[i] >= 0){
      int pos = lbase[bn[i]] + rk[i];
      sorted[pos] = rec[i];
      binOf[pos]  = (unsigned short)bn[i];
    }
  }
  __syncthreads();
  for (int idx = t; idx < ecnt; idx += 256){
    int b = binOf[idx];
    int gpos = gbase[b] + (idx - lbase[b]);
    if (gpos < RCAP) bucketed[(size_t)b * RCAP + gpos] = sorted[idx];
  }
  // ---- W1-prep tail (blocks 0..63): bf16 hi/lo split ----
  {
    int gid = blockIdx.x * 256 + t;
    if (gid < 16384){
      int k = gid >> 7, n = gid & 127;
      float x = W1[gid];
      unsigned u = __float_as_uint(x);
      short hs = (short)(u >> 16);
      float hf = __uint_as_float(u & 0xFFFF0000u);
      short ls = (short)(__float_as_uint(x - hf) >> 16);
      planes[n * 128 + k]         = hs;
      planes[16384 + n * 128 + k] = ls;
    }
  }
  // ---- W' fold tail (blocks 64..191): one W2 row per block ----
  if (blockIdx.x >= 64 && blockIdx.x < 192){
    int b = blockIdx.x - 64;
    if (t < 128) w2row[t] = W2[b * 128 + t];
    __syncthreads();
    int mat = t >> 7, n = t & 127;
    const float* Wsrc = Wm1 + (size_t)mat * 16384;
    float acc = 0.f;
    #pragma unroll 4
    for (int j = 0; j < 128; j++) acc = fmaf(w2row[j], Wsrc[j * 128 + n], acc);
    __half hh = __float2half(acc);
    __half ll = __float2half(acc - __half2float(hh));
    planes[(size_t)(4 + 2 * mat) * 16384 + n * 128 + b] = __half_as_short(hh);
    planes[(size_t)(5 + 2 * mat) * 16384 + n * 128 + b] = __half_as_short(ll);
  } else if (blockIdx.x == 192){
    if (t < 128){
      float acc = bm1[t];
      for (int j = 0; j < 128; j++)
        acc += b2[j] * (Wm1[j * 128 + t] + Wm1[(128 + j) * 128 + t]);
      bm1p[t] = acc;
      zbias[t] = 0.f;
    }
  }
}

// ---------------- Fused launch: gemm_f32 (blocks < gemmBlocks) || binB (rest) ----------------
// gemm side writes UNscaled t1 = x@W1 (dinv produced by binB in same dispatch).
__global__ __launch_bounds__(512, 4) void fused_gemm_binB(
    const float* __restrict__ X, const short* __restrict__ Whi_,
    const short* __restrict__ Wlo_, __half* __restrict__ O, int nrows, int gemmBlocks,
    const unsigned* __restrict__ bucketed, const int* __restrict__ gcur,
    int* __restrict__ rows_sorted, int* __restrict__ offs,
    int* __restrict__ counts, float* __restrict__ dinv, int N){
  __shared__ __align__(16) char smem[40960];
  int t = threadIdx.x;
  if (blockIdx.x < gemmBlocks){
    short* Xhi = (short*)smem;
    short* Xlo = Xhi + 128 * KST;
    short* Whi = Xlo + 128 * KST;
    short* Wlo = Whi + 128 * KST;
    int w = t >> 6, lane = t & 63;
    int m = lane & 15, q = lane >> 4;
    int row0 = blockIdx.x * 128;
    floatx4 acc[8];
    #pragma unroll
    for (int ct = 0; ct < 8; ct++) acc[ct] = (floatx4)0.f;
    for (int kc = 0; kc < 4; kc++){
      int k0 = kc * 32;
      __syncthreads();
      #pragma unroll
      for (int qq = 0; qq < 2; qq++){
        int f = t + 512 * qq;
        int r = f >> 3, kq = f & 7;
        int gr = row0 + r;
        int grc = (gr < nrows) ? gr : 0;
        float4 v = *(const float4*)(X + (size_t)grc * NCH + k0 + kq * 4);
        short h[4], l[4];
        float vv[4] = {v.x, v.y, v.z, v.w};
        #pragma unroll
        for (int j = 0; j < 4; j++){
          unsigned u = __float_as_uint(vv[j]);
          h[j] = (short)(u >> 16);
          float hf = __uint_as_float(u & 0xFFFF0000u);
          l[j] = (short)(__float_as_uint(vv[j] - hf) >> 16);
        }
        *(uint2*)(Xhi + r * KST + kq * 4) = *(uint2*)h;
        *(uint2*)(Xlo + r * KST + kq * 4) = *(uint2*)l;
      }
      {
        int n = t >> 2, kq = t & 3;
        *(uint4*)(Whi + n * KST + kq * 8) = *(const uint4*)(Whi_ + n * NCH + k0 + kq * 8);
        *(uint4*)(Wlo + n * KST + kq * 8) = *(const uint4*)(Wlo_ + n * NCH + k0 + kq * 8);
      }
      __syncthreads();
      short8 a_hi = *(const short8*)(Xhi + (w * 16 + m) * KST + q * 8);
      short8 a_lo = *(const short8*)(Xlo + (w * 16 + m) * KST + q * 8);
      #pragma unroll
      for (int ct = 0; ct < 8; ct++){
        short8 b_hi = *(const short8*)(Whi + (ct * 16 + m) * KST + q * 8);
        short8 b_lo = *(const short8*)(Wlo + (ct * 16 + m) * KST + q * 8);
        acc[ct] = __builtin_amdgcn_mfma_f32_16x16x32_bf16(a_hi, b_hi, acc[ct], 0, 0, 0);
        acc[ct] = __builtin_amdgcn_mfma_f32_16x16x32_bf16(a_lo, b_hi, acc[ct], 0, 0, 0);
        acc[ct] = __builtin_amdgcn_mfma_f32_16x16x32_bf16(a_hi, b_lo, acc[ct], 0, 0, 0);
      }
    }
    #pragma unroll
    for (int r = 0; r < 4; r++){
      int grow = row0 + w * 16 + q * 4 + r;
      if (grow < nrows){
        #pragma unroll
        for (int ct = 0; ct < 8; ct++)
          O[(size_t)grow * NCH + ct * 16 + m] = __float2half(acc[ct][r]);
      }
    }
  } else {
    // ---- binB: per-bucket LDS counting sort -> CSR (fixed slabs) ----
    int b = blockIdx.x - gemmBlocks;
    unsigned* ledge = (unsigned*)smem;              // RCAP
    int* cnt  = (int*)(smem + RCAP * 4);            // 256
    int* cnt2 = cnt + 256;
    int* lex  = cnt2 + 256;
    int* sh   = lex + 256;
    int size = min(gcur[b], RCAP);
    int n0 = b * G_NODES;
    if (t < 256){ cnt[t] = 0; cnt2[t] = 0; }
    __syncthreads();
    for (int i = t; i < size; i += 512){
      unsigned v = bucketed[(size_t)b * RCAP + i];
      ledge[i] = v;
      atomicAdd(&cnt[v >> 17], 1);
    }
    __syncthreads();
    {
      int v = (t < 256) ? cnt[t] : 0;
      if (t < 256) sh[t] = v;
      __syncthreads();
      for (int off = 1; off < 256; off <<= 1){
        int val = (t >= off && t < 256) ? sh[t - off] : 0;
        __syncthreads();
        if (t < 256) sh[t] += val;
        __syncthreads();
      }
      if (t < 256){
        lex[t] = sh[t] - v;
        int n = n0 + t;
        if (n < N){
          counts[n] = v;
          offs[n]   = b * RCAP + sh[t] - v;
          dinv[n]   = rsqrtf((float)v + 1.0f);
        }
      }
    }
    __syncthreads();
    for (int i = t; i < size; i += 512){
      unsigned v = ledge[i];
      int node = v >> 17;
      int pos = lex[node] + atomicAdd(&cnt2[node], 1);
      rows_sorted[(size_t)b * RCAP + pos] = (int)(v & 0x1FFFFu);
    }
  }
}

// ---------------- GEMM (fp16 input): 2-MFMA f16, NCT col-tiles, opt. dinv scale ----------------
template<int NCT>
__global__ __launch_bounds__(512, 4) void gemm_f16k(
    const __half* __restrict__ X,
    const short* __restrict__ Whi0, const short* __restrict__ Wlo0,
    const short* __restrict__ Whi1, const short* __restrict__ Wlo1,
    const float* __restrict__ scale, int do_scale,
    __half* __restrict__ O0, __half* __restrict__ O1, int nrows){
  __shared__ short Xs[128 * KST];
  __shared__ short Whs[NCT * 16 * KST];
  __shared__ short Wls[NCT * 16 * KST];
  int t = threadIdx.x;
  int w = t >> 6, lane = t & 63;
  int m = lane & 15, q = lane >> 4;
  int row0 = blockIdx.x * 128;
  floatx4 acc[NCT];
  #pragma unroll
  for (int ct = 0; ct < NCT; ct++) acc[ct] = (floatx4)0.f;

  for (int kc = 0; kc < 4; kc++){
    int k0 = kc * 32;
    __syncthreads();
    {
      int r = t >> 2, kq = t & 3;
      int gr = row0 + r;
      int grc = (gr < nrows) ? gr : 0;
      *(uint4*)(Xs + r * KST + kq * 8) = *(const uint4*)(X + (size_t)grc * NCH + k0 + kq * 8);
    }
    #pragma unroll
    for (int i = t; i < NCT * 16 * 4; i += 512){
      int n = i >> 2, kq = i & 3;
      const short* sh = (n < 128) ? (Whi0 + n * NCH) : (Whi1 + (n - 128) * NCH);
      const short* sl = (n < 128) ? (Wlo0 + n * NCH) : (Wlo1 + (n - 128) * NCH);
      *(uint4*)(Whs + n * KST + kq * 8) = *(const uint4*)(sh + k0 + kq * 8);
      *(uint4*)(Wls + n * KST + kq * 8) = *(const uint4*)(sl + k0 + kq * 8);
    }
    __syncthreads();
    half8 a = *(const half8*)(Xs + (w * 16 + m) * KST + q * 8);
    #pragma unroll
    for (int ct = 0; ct < NCT; ct++){
      half8 bh = *(const half8*)(Whs + (ct * 16 + m) * KST + q * 8);
      half8 bl = *(const half8*)(Wls + (ct * 16 + m) * KST + q * 8);
      acc[ct] = __builtin_amdgcn_mfma_f32_16x16x32_f16(a, bh, acc[ct], 0, 0, 0);
      acc[ct] = __builtin_amdgcn_mfma_f32_16x16x32_f16(a, bl, acc[ct], 0, 0, 0);
    }
  }
  #pragma unroll
  for (int r = 0; r < 4; r++){
    int grow = row0 + w * 16 + q * 4 + r;
    if (grow < nrows){
      float sc = do_scale ? scale[grow] : 1.0f;
      #pragma unroll
      for (int ct = 0; ct < NCT; ct++){
        __half val = __float2half(acc[ct][r] * sc);
        if (ct < 8) O0[(size_t)grow * NCH + ct * 16 + m] = val;
        else        O1[(size_t)grow * NCH + (ct - 8) * 16 + m] = val;
      }
    }
  }
}

// ---------------- GCN aggregation: wave per node, 16B/lane gathers ----------------
// edge_dinv=1: s unscaled, gather dinv[r] per edge.
// edge_dinv=0: s pre-scaled by dinv (plain adds).
__global__ __launch_bounds__(256) void agg_kernel(
    const __half* __restrict__ s, const float* __restrict__ dinv,
    const int* __restrict__ offs, const int* __restrict__ counts,
    const int* __restrict__ rows_sorted, const float* __restrict__ bias,
    __half* __restrict__ outp, int N, int do_relu, int edge_dinv){
  int wave = (int)((blockIdx.x * blockDim.x + threadIdx.x) >> 6);
  int lane = threadIdx.x & 63;
  if (wave >= N) return;
  int c = wave;
  int g = lane >> 4, h = lane & 15;
  float di = dinv[c];
  float wself = edge_dinv ? di : 1.0f;
  float acc[8] = {0.f,0.f,0.f,0.f,0.f,0.f,0.f,0.f};
  if (g == 0){
    uint4 v = *(const uint4*)(s + (size_t)c * NCH + h * 8);
    const __half2* hp = (const __half2*)&v;
    #pragma unroll
    for (int i = 0; i < 4; i++){
      float2 f = __half22float2(hp[i]);
      acc[2*i] = fmaf(wself, f.x, acc[2*i]); acc[2*i+1] = fmaf(wself, f.y, acc[2*i+1]);
    }
  }
  int off = offs[c], cnt = counts[c];
  for (int chunk = 0; chunk < cnt; chunk += 64){
    int nn = min(64, cnt - chunk);
    int myidx = (lane < nn) ? rows_sorted[off + chunk + lane] : 0;
    float mydinv = 1.0f;
    if (edge_dinv && lane < nn) mydinv = dinv[myidx];
    int jmax = (nn + 3) >> 2;
    #pragma unroll 8
    for (int j = 0; j < jmax; j++){
      int e = 4 * j + g;
      int r  = __shfl(myidx, e & 63, 64);
      float dr = edge_dinv ? __shfl(mydinv, e & 63, 64) : 1.0f;
      if (e < nn){
        uint4 v = *(const uint4*)(s + (size_t)r * NCH + h * 8);
        const __half2* hp = (const __half2*)&v;
        #pragma unroll
        for (int i = 0; i < 4; i++){
          float2 f = __half22float2(hp[i]);
          acc[2*i] = fmaf(dr, f.x, acc[2*i]); acc[2*i+1] = fmaf(dr, f.y, acc[2*i+1]);
        }
      }
    }
  }
  #pragma unroll
  for (int i = 0; i < 8; i++){
    acc[i] += __shfl_xor(acc[i], 16, 64);
    acc[i] += __shfl_xor(acc[i], 32, 64);
  }
  if (g == 0){
    float4 b0 = *(const float4*)(bias + h * 8);
    float4 b1 = *(const float4*)(bias + h * 8 + 4);
    float o[8];
    o[0] = di*acc[0]+b0.x; o[1] = di*acc[1]+b0.y; o[2] = di*acc[2]+b0.z; o[3] = di*acc[3]+b0.w;
    o[4] = di*acc[4]+b1.x; o[5] = di*acc[5]+b1.y; o[6] = di*acc[6]+b1.z; o[7] = di*acc[7]+b1.w;
    if (do_relu){
      #pragma unroll
      for (int i = 0; i < 8; i++) o[i] = fmaxf(o[i], 0.f);
    }
    __half2 packed[4];
    #pragma unroll
    for (int i = 0; i < 4; i++) packed[i] = __floats2half2_rn(o[2*i], o[2*i+1]);
    *(uint4*)(outp + (size_t)c * NCH + h * 8) = *(uint4*)packed;
  }
}

// ---------------- Pair head: wave per 16 pairs (32 gathers in flight), 16B/lane ----------------
__global__ __launch_bounds__(256) void pair_kernel(
    const __half* __restrict__ A, const __half* __restrict__ B,
    const int* __restrict__ src, const int* __restrict__ dst,
    const float* __restrict__ bm1, const float* __restrict__ Wm2,
    const float* __restrict__ bm2, float* __restrict__ outp, int P){
  int gwave = (int)((blockIdx.x * blockDim.x + threadIdx.x) >> 6);
  int lane  = threadIdx.x & 63;
  int nw    = (int)((gridDim.x * blockDim.x) >> 6);
  int g = lane >> 4, h = lane & 15;
  float bb[8], ww[8];
  {
    float4 t0 = *(const float4*)(bm1 + h * 8);
    float4 t1 = *(const float4*)(bm1 + h * 8 + 4);
    bb[0]=t0.x; bb[1]=t0.y; bb[2]=t0.z; bb[3]=t0.w;
    bb[4]=t1.x; bb[5]=t1.y; bb[6]=t1.z; bb[7]=t1.w;
    float4 w0 = *(const float4*)(Wm2 + h * 8);
    float4 w1 = *(const float4*)(Wm2 + h * 8 + 4);
    ww[0]=w0.x; ww[1]=w0.y; ww[2]=w0.z; ww[3]=w0.w;
    ww[4]=w1.x; ww[5]=w1.y; ww[6]=w1.z; ww[7]=w1.w;
  }
  float bsc = bm2[0];
  const __half* basep = (g & 1) ? B : A;
  const int* idxp = (g & 1) ? dst : src;
  int s = g >> 1;
  for (int p0 = gwave * 16; p0 < P; p0 += nw * 16){
    int pi[8]; uint4 v[8];
    #pragma unroll
    for (int k = 0; k < 8; k++){
      int p = p0 + 2 * k + s;
      pi[k] = p;
      int px = (p < P) ? p : P - 1;
      int node = idxp[px];
      v[k] = *(const uint4*)(basep + (size_t)node * NCH + h * 8);
    }
    float pr[8];
    #pragma unroll
    for (int k = 0; k < 8; k++){
      const __half2* hp = (const __half2*)&v[k];
      float f[8];
      #pragma unroll
      for (int i = 0; i < 4; i++){
        float2 t2 = __half22float2(hp[i]);
        f[2*i] = t2.x; f[2*i+1] = t2.y;
      }
      float p_ = 0.f;
      #pragma unroll
      for (int i = 0; i < 8; i++){
        float o = __shfl_xor(f[i], 16, 64);
        p_ += fmaxf(f[i] + o + bb[i], 0.f) * ww[i];
      }
      pr[k] = p_;
    }
    #pragma unroll
    for (int k = 0; k < 8; k++){
      #pragma unroll
      for (int d = 1; d <= 8; d <<= 1) pr[k] += __shfl_xor(pr[k], d, 64);
    }
    if ((lane & 31) == 0){
      #pragma unroll
      for (int k = 0; k < 8; k++)
        if (pi[k] < P) outp[pi[k]] = pr[k] + bsc;
    }
  }
}

// ---------------- launch ----------------

extern "C" void kernel_launch(void* const* d_in, const int* in_sizes, int n_in,
                              void* d_out, int out_size, void* d_ws, size_t ws_size,
                              hipStream_t stream){
  const float* x   = (const float*)d_in[0];
  const int*   ei  = (const int*)  d_in[1];
  const int*   ep  = (const int*)  d_in[2];
  const float* W1  = (const float*)d_in[3];
  const float* b1  = (const float*)d_in[4];
  const float* W2  = (const float*)d_in[5];
  const float* b2  = (const float*)d_in[6];
  const float* Wm1 = (const float*)d_in[7];
  const float* bm1 = (const float*)d_in[8];
  const float* Wm2 = (const float*)d_in[9];
  const float* bm2 = (const float*)d_in[10];
  float* outp = (float*)d_out;

  const int N = in_sizes[0] / NCH;
  const int E = in_sizes[1] / 2;
  const int P = in_sizes[2] / 2;
  const int NB = (N + G_NODES - 1) / G_NODES;

  char* base = (char*)d_ws;
  size_t off = 0;
  int*      counts      = (int*)     (base + off); off = align256(off + (size_t)N * 4);
  int*      offs        = (int*)     (base + off); off = align256(off + (size_t)N * 4);
  float*    dinv        = (float*)   (base + off); off = align256(off + (size_t)N * 4);
  int*      gcur        = (int*)     (base + off); off = align256(off + (size_t)NB * 4);
  unsigned* bucketed    = (unsigned*)(base + off); off = align256(off + (size_t)NB * RCAP * 4);
  int*      rows_sorted = (int*)     (base + off); off = align256(off + (size_t)NB * RCAP * 4);
  short*    planes      = (short*)   (base + off); off = align256(off + (size_t)8 * 16384 * 2);
  float*    bm1p        = (float*)   (base + off); off = align256(off + (size_t)256 * 4);
  float*    zbias       = (float*)   (base + off); off = align256(off + (size_t)128 * 4);
  __half*   s1buf       = (__half*)  (base + off); off = align256(off + (size_t)N * NCH * 2);
  __half*   h1buf       = (__half*)  (base + off); off = align256(off + (size_t)N * NCH * 2);
  __half*   zbuf        = (__half*)  (base + off); off = align256(off + (size_t)N * NCH * 2);
  __half*   sA          = (__half*)  (base + off); off = align256(off + (size_t)N * NCH * 2);
  __half*   sB          = (__half*)  (base + off); off = align256(off + (size_t)N * NCH * 2);
  (void)ws_size; (void)n_in; (void)out_size;

  short* W1hi = planes + 0 * 16384;
  short* W1lo = planes + 1 * 16384;
  short* Wahi = planes + 4 * 16384;   // WA' = W2@Wa (hi)
  short* Walo = planes + 5 * 16384;   // WA' (lo)
  short* Wbhi = planes + 6 * 16384;   // WB' = W2@Wb (hi)
  short* Wblo = planes + 7 * 16384;   // WB' (lo)

  const int* row = ei;       // edge_index[0] = source
  const int* col = ei + E;   // edge_index[1] = target
  const int* psrc = ep;
  const int* pdst = ep + P;

  int gemm_grid = (N + 127) / 128;
  int agg_grid  = (N + 3) / 4;
  int binA_grid = (E + EPB - 1) / EPB;
  if (binA_grid < 193) binA_grid = 193;   // W'-fold tail needs blocks 64..192

  // 0: zero bucket cursors
  hipMemsetAsync(gcur, 0, (size_t)NB * 4, stream);
  // 1: edge bucketing + W1/W'-fold/bias tails
  binA_kernel<<<binA_grid, 256, 0, stream>>>(row, col, gcur, bucketed, E, NB,
                                             W1, W2, Wm1, b2, bm1, planes, bm1p, zbias);
  // 2: fused conv1 GEMM (t1 = x@W1, UNscaled) || CSR finalize (no shared data -> no race)
  fused_gemm_binB<<<gemm_grid + NB, 512, 0, stream>>>(
      x, W1hi, W1lo, s1buf, N, gemm_grid,
      bucketed, gcur, rows_sorted, offs, counts, dinv, N);
  // 3: conv1 agg (edge-dinv): h1 = relu(dinv*(dinv*t1[c]+sum dinv[r]t1[r])+b1)
  agg_kernel<<<agg_grid, 256, 0, stream>>>(s1buf, dinv, offs, counts, rows_sorted, b1, h1buf, N, 1, 1);
  // 4: conv2 agg (edge-dinv, zero bias, no relu): z = dinv*(dinv*h1[c]+sum dinv[r]h1[r])
  agg_kernel<<<agg_grid, 256, 0, stream>>>(h1buf, dinv, offs, counts, rows_sorted, zbias, zbuf, N, 0, 1);
  // 5: pair precompute (dual, folded): sA = z@WA', sB = z@WB'
  gemm_f16k<16><<<gemm_grid, 512, 0, stream>>>(zbuf, Wahi, Walo, Wbhi, Wblo, dinv, 0, sA, sB, N);
  // 6: out[p] = relu(A[src]+B[dst]+bm1')@Wm2 + bm2
  pair_kernel<<<8192, 256, 0, stream>>>(sA, sB, psrc, pdst, bm1p, Wm2, bm2, outp, P);
}